// Round 3
// baseline (517.397 us; speedup 1.0000x reference)
//
#include <hip/hip_runtime.h>
#include <math.h>

constexpr int NPIX  = 262144;   // 512*512
constexpr int NLAB  = 8;
constexpr int NITER = 5;        // Newton-Schulz iterations

// ---------------- workspace layout (4B-element offsets), runtime nblk ----------------
__host__ __device__ inline size_t offMpart()         { return 0; }
__host__ __device__ inline size_t offSpart(int nblk) { return (size_t)2*nblk*8*4096; }
__host__ __device__ inline size_t offCnt(int nblk)   { return offSpart(nblk) + (size_t)2*nblk*8*64; }
__host__ __device__ inline size_t offMR(int nblk)    { return offCnt(nblk) + (size_t)2*nblk*8; }
__host__ __device__ inline size_t offSR(int nblk)    { return offMR(nblk) + 2*8*4096; }
__host__ __device__ inline size_t offCR(int nblk)    { return offSR(nblk) + 2*8*64; }
__host__ __device__ inline size_t offWH(int nblk)    { return offCR(nblk) + 16; }
__host__ __device__ inline size_t offCO(int nblk)    { return offWH(nblk) + 8*4096; }
__host__ __device__ inline size_t offT(int nblk)     { return offCO(nblk) + 8*4096; }
__host__ __device__ inline size_t offBIAS(int nblk)  { return offT(nblk) + 8*4096; }
__host__ __device__ inline size_t offMUC(int nblk)   { return offBIAS(nblk) + 8*64; }
__host__ __device__ inline size_t offMUS(int nblk)   { return offMUC(nblk) + 8*64; }
__host__ __device__ inline size_t offVALID(int nblk) { return offMUS(nblk) + 8*64; }
// sort arrays (int storage in same buffer)
__host__ __device__ inline size_t offHISTi(int nblk) { return offVALID(nblk) + 8; }     // [256][8]
__host__ __device__ inline size_t offOFFSi(int nblk) { return offHISTi(nblk) + 2048; }  // [256][8]
__host__ __device__ inline size_t offMETAi(int nblk) { return offOFFSi(nblk) + 2048; }  // [32]
__host__ __device__ inline size_t offGRPLi(int nblk) { return offMETAi(nblk) + 32; }    // [4112]
__host__ __device__ inline size_t offSIDXi(int nblk) { return offGRPLi(nblk) + 4112; }  // [262656]
__host__ __device__ inline size_t offEnd(int nblk)   { return offSIDXi(nblk) + 262656; }

// =====================================================================
// K1: single-pass per-label moments (unchanged from round 2).
// =====================================================================
__global__ __launch_bounds__(512, 2) void k_moments(
    const float* __restrict__ cont, const float* __restrict__ styl,
    const int* __restrict__ cseg, const int* __restrict__ sseg,
    float* __restrict__ ws, int nblk)
{
  const int t = blockIdx.y, blk = blockIdx.x;
  const float* __restrict__ X  = t ? styl : cont;
  const int*  __restrict__ seg = t ? sseg : cseg;
  const int tid = threadIdx.x, lane = tid & 63, wv = tid >> 6;

  __shared__ float xs[256 * 64];   // exactly 64 KB

  const int r0 = (lane >> 3) << 3;
  const int c0 = (lane & 7) << 3;

  float acc[8][8];
  #pragma unroll
  for (int i = 0; i < 8; ++i)
    #pragma unroll
    for (int j = 0; j < 8; ++j) acc[i][j] = 0.f;
  float ssum = 0.f;
  int   cnt  = 0;

  const int chunk = NPIX / nblk;
  const int pbase = blk * chunk;
  const int nph   = chunk >> 8;
  const int ci  = tid >> 5;
  const int pxi = (tid & 31) << 2;
  const int swW = (tid & 7) << 2;

  for (int ph = 0; ph < nph; ++ph) {
    const int p0 = pbase + (ph << 8);
    float4 v[8];
    #pragma unroll
    for (int q = 0; q < 8; ++q) {
      const int c  = ci + ((q & 3) << 4);
      const int px = pxi + ((q >> 2) << 7);
      v[q] = *reinterpret_cast<const float4*>(&X[(size_t)c * NPIX + p0 + px]);
    }
    int lb[4];
    #pragma unroll
    for (int g = 0; g < 4; ++g) lb[g] = seg[p0 + (g << 6) + lane];

    __syncthreads();
    #pragma unroll
    for (int q = 0; q < 8; ++q) {
      const int c  = ci + ((q & 3) << 4);
      const int px = pxi + ((q >> 2) << 7);
      const int pc = c ^ swW;
      xs[(px + 0) * 64 + pc] = v[q].x;
      xs[(px + 1) * 64 + pc] = v[q].y;
      xs[(px + 2) * 64 + pc] = v[q].z;
      xs[(px + 3) * 64 + pc] = v[q].w;
    }
    __syncthreads();

    for (int g = 0; g < 4; ++g) {
      unsigned long long m = __ballot(lb[g] == wv);
      cnt += __popcll(m);
      while (m) {
        const int j = (g << 6) + __builtin_ctzll(m);
        m &= m - 1;
        const int sw = j & 28;
        const float4 a0 = *reinterpret_cast<const float4*>(&xs[j * 64 + (r0 ^ sw)]);
        const float4 a1 = *reinterpret_cast<const float4*>(&xs[j * 64 + ((r0 ^ sw) ^ 4)]);
        const float4 b0 = *reinterpret_cast<const float4*>(&xs[j * 64 + (c0 ^ sw)]);
        const float4 b1 = *reinterpret_cast<const float4*>(&xs[j * 64 + ((c0 ^ sw) ^ 4)]);
        ssum += xs[j * 64 + (lane ^ sw)];
        const float av[8] = {a0.x, a0.y, a0.z, a0.w, a1.x, a1.y, a1.z, a1.w};
        const float bv[8] = {b0.x, b0.y, b0.z, b0.w, b1.x, b1.y, b1.z, b1.w};
        #pragma unroll
        for (int i = 0; i < 8; ++i)
          #pragma unroll
          for (int jj = 0; jj < 8; ++jj) acc[i][jj] += av[i] * bv[jj];
      }
    }
  }

  float* Md = ws + offMpart() + (size_t)((t * nblk + blk) * 8 + wv) * 4096;
  #pragma unroll
  for (int i = 0; i < 8; ++i) {
    *reinterpret_cast<float4*>(&Md[(r0 + i) * 64 + c0]) =
        make_float4(acc[i][0], acc[i][1], acc[i][2], acc[i][3]);
    *reinterpret_cast<float4*>(&Md[(r0 + i) * 64 + c0 + 4]) =
        make_float4(acc[i][4], acc[i][5], acc[i][6], acc[i][7]);
  }
  ws[offSpart(nblk) + (size_t)((t * nblk + blk) * 8 + wv) * 64 + lane] = ssum;
  if (lane == 0) ws[offCnt(nblk) + (size_t)(t * nblk + blk) * 8 + wv] = (float)cnt;
}

// =====================================================================
// K1b: reduce partials over nblk (unchanged).
// =====================================================================
__global__ __launch_bounds__(256) void k_reduce(float* __restrict__ ws, int nblk)
{
  const int b = blockIdx.x;
  const int sgm = b & 15, tl = b >> 4, l = tl & 7, t = tl >> 3;
  const int tid = threadIdx.x;
  const size_t stride = (size_t)8 * 4096;
  const float* src = ws + offMpart() + (size_t)(t * nblk) * stride + (size_t)l * 4096 + sgm * 256 + tid;
  float s = 0.f;
  for (int bb = 0; bb < nblk; ++bb) s += src[bb * stride];
  ws[offMR(nblk) + (size_t)tl * 4096 + sgm * 256 + tid] = s;
  if (sgm == 0) {
    if (tid < 64) {
      float q = 0.f;
      for (int bb = 0; bb < nblk; ++bb)
        q += ws[offSpart(nblk) + (size_t)((t * nblk + bb) * 8 + l) * 64 + tid];
      ws[offSR(nblk) + tl * 64 + tid] = q;
    } else if (tid == 64) {
      float q = 0.f;
      for (int bb = 0; bb < nblk; ++bb)
        q += ws[offCnt(nblk) + (size_t)(t * nblk + bb) * 8 + l];
      ws[offCR(nblk) + tl] = q;
    }
  }
}

// =====================================================================
// 64x64 symmetric-operand matmul on LDS (unchanged).
// =====================================================================
__device__ __forceinline__ void mm64s4(float* __restrict__ dst,
    const float* __restrict__ A, const float* __restrict__ B,
    int tid, float p0, float p1)
{
  const int lane = tid & 63, wv = tid >> 6;
  const int r0 = (wv << 4) + ((lane >> 4) << 2);
  const int c0 = (lane & 15) << 2;
  float acc[4][4];
  #pragma unroll
  for (int i = 0; i < 4; ++i)
    #pragma unroll
    for (int j = 0; j < 4; ++j) acc[i][j] = 0.f;
  #pragma unroll 4
  for (int k = 0; k < 64; ++k) {
    const float4 a = *reinterpret_cast<const float4*>(&A[k * 64 + r0]);
    const float4 b = *reinterpret_cast<const float4*>(&B[k * 64 + c0]);
    const float av[4] = {a.x, a.y, a.z, a.w};
    const float bv[4] = {b.x, b.y, b.z, b.w};
    #pragma unroll
    for (int i = 0; i < 4; ++i)
      #pragma unroll
      for (int j = 0; j < 4; ++j) acc[i][j] += av[i] * bv[j];
  }
  #pragma unroll
  for (int i = 0; i < 4; ++i) {
    float4 o;
    o.x = p1 * acc[i][0] + (((r0 + i) == (c0 + 0)) ? p0 : 0.f);
    o.y = p1 * acc[i][1] + (((r0 + i) == (c0 + 1)) ? p0 : 0.f);
    o.z = p1 * acc[i][2] + (((r0 + i) == (c0 + 2)) ? p0 : 0.f);
    o.w = p1 * acc[i][3] + (((r0 + i) == (c0 + 3)) ? p0 : 0.f);
    *reinterpret_cast<float4*>(&dst[(r0 + i) * 64 + c0]) = o;
  }
}

// =====================================================================
// K2: cov build + coupled Newton-Schulz; final iteration computes only
// the needed product (Z for t=0, Y for t=1).
// =====================================================================
__global__ __launch_bounds__(256) void k_ns(float* __restrict__ ws, int nblk)
{
  const int l = blockIdx.x & 7, t = blockIdx.x >> 3;
  const int tid = threadIdx.x;
  __shared__ float bA[4096], bY[4096], bZ[4096], bT[4096];
  float* svec   = bT;
  float* rowsum = bT + 64;
  float* scal   = bT + 128;

  const float n0 = ws[offCR(nblk) + l];
  const float n1 = ws[offCR(nblk) + 8 + l];
  const float n = t ? n1 : n0;
  const bool valid = (n0 > 10.f) && (n1 > 10.f) && (n0 < 100.f * n1) && (n1 < 100.f * n0);
  if (tid < 64) svec[tid] = ws[offSR(nblk) + (t * 8 + l) * 64 + tid];
  __syncthreads();

  const float invn = 1.f / fmaxf(n, 1.f);
  const float nm1  = n - 1.f;
  const float rdiv = 1.f / ((nm1 == 0.f) ? 1e-5f : nm1);
  const int i0 = tid >> 2, jb = (tid & 3) << 4;
  const float Si = svec[i0];
  const float* MRp = ws + offMR(nblk) + (size_t)(t * 8 + l) * 4096;
  #pragma unroll
  for (int q = 0; q < 4; ++q) {
    const int j = jb + (q << 2);
    const float4 m  = *reinterpret_cast<const float4*>(&MRp[i0 * 64 + j]);
    const float4 sj = *reinterpret_cast<const float4*>(&svec[j]);
    float4 a;
    a.x = (m.x - Si * sj.x * invn) * rdiv + ((t == 0 && i0 == j + 0) ? 1.f : 0.f);
    a.y = (m.y - Si * sj.y * invn) * rdiv + ((t == 0 && i0 == j + 1) ? 1.f : 0.f);
    a.z = (m.z - Si * sj.z * invn) * rdiv + ((t == 0 && i0 == j + 2) ? 1.f : 0.f);
    a.w = (m.w - Si * sj.w * invn) * rdiv + ((t == 0 && i0 == j + 3) ? 1.f : 0.f);
    *reinterpret_cast<float4*>(&bA[i0 * 64 + j]) = a;
  }
  if (tid < 64) ws[(t ? offMUS(nblk) : offMUC(nblk)) + l * 64 + tid] = svec[tid] * invn;
  if (t == 0 && tid == 0) ws[offVALID(nblk) + l] = valid ? 1.f : 0.f;
  __syncthreads();

  if (tid < 64) {
    float s = 0.f;
    for (int j = 0; j < 64; ++j) s += fabsf(bA[j * 64 + tid]);
    rowsum[tid] = s;
  }
  __syncthreads();
  if (tid == 0) {
    float c = 0.f;
    for (int i = 0; i < 64; ++i) c = fmaxf(c, rowsum[i]);
    scal[0] = fmaxf(c, 1e-20f);
  }
  __syncthreads();
  const float cval = scal[0];
  const float rc = 1.f / cval;
  __syncthreads();

  #pragma unroll
  for (int q = 0; q < 4; ++q) {
    const int j = jb + (q << 2);
    float4 a = *reinterpret_cast<const float4*>(&bA[i0 * 64 + j]);
    a.x *= rc; a.y *= rc; a.z *= rc; a.w *= rc;
    *reinterpret_cast<float4*>(&bY[i0 * 64 + j]) = a;
    float4 z;
    z.x = (i0 == j + 0) ? 1.f : 0.f; z.y = (i0 == j + 1) ? 1.f : 0.f;
    z.z = (i0 == j + 2) ? 1.f : 0.f; z.w = (i0 == j + 3) ? 1.f : 0.f;
    *reinterpret_cast<float4*>(&bZ[i0 * 64 + j]) = z;
  }
  __syncthreads();

  float *Y = bY, *Z = bZ, *T = bT, *Wb = bA;
  for (int it = 0; it < NITER - 1; ++it) {
    mm64s4(T, Z, Y, tid, 1.5f, -0.5f); __syncthreads();
    mm64s4(Wb, Y, T, tid, 0.f, 1.f);   __syncthreads();
    mm64s4(Y, T, Z, tid, 0.f, 1.f);    __syncthreads();
    float* nz = Y; Y = Wb; Wb = Z; Z = nz;
  }
  // final iteration: only the needed product
  mm64s4(T, Z, Y, tid, 1.5f, -0.5f); __syncthreads();
  if (t) mm64s4(Wb, Y, T, tid, 0.f, 1.f);   // Y_final
  else   mm64s4(Wb, T, Z, tid, 0.f, 1.f);   // Z_final
  __syncthreads();

  const float osc = t ? sqrtf(cval) : (1.0f / sqrtf(cval));
  float* dst = ws + (t ? offCO(nblk) : offWH(nblk)) + (size_t)l * 4096;
  #pragma unroll
  for (int q = 0; q < 4; ++q) {
    const int j = jb + (q << 2);
    float4 v = *reinterpret_cast<const float4*>(&Wb[i0 * 64 + j]);
    v.x *= osc; v.y *= osc; v.z *= osc; v.w *= osc;
    *reinterpret_cast<float4*>(&dst[i0 * 64 + j]) = v;
  }
}

// =====================================================================
// K2b: T_l = CO_l @ WH_l (identity if invalid), bias = mus - T@muc (0 if invalid)
// =====================================================================
__global__ __launch_bounds__(256) void k_tmat(float* __restrict__ ws, int nblk)
{
  const int l = blockIdx.x;
  const int tid = threadIdx.x;
  __shared__ float Am[4096], Bm[4096];
  __shared__ float red[64];
  __shared__ float mucS[64], musS[64];
  const bool valid = ws[offVALID(nblk) + l] > 0.5f;
  if (tid < 64) {
    red[tid] = 0.f;
    mucS[tid] = ws[offMUC(nblk) + l * 64 + tid];
    musS[tid] = ws[offMUS(nblk) + l * 64 + tid];
  }
  #pragma unroll
  for (int q = 0; q < 4; ++q) {
    const int e = tid * 4 + q * 1024;
    *reinterpret_cast<float4*>(&Am[e]) =
        *reinterpret_cast<const float4*>(&ws[offCO(nblk) + (size_t)l * 4096 + e]);
    *reinterpret_cast<float4*>(&Bm[e]) =
        *reinterpret_cast<const float4*>(&ws[offWH(nblk) + (size_t)l * 4096 + e]);
  }
  __syncthreads();
  const int lane = tid & 63, wv = tid >> 6;
  const int r0 = (wv << 4) + ((lane >> 4) << 2);
  const int c0 = (lane & 15) << 2;
  float acc[4][4];
  #pragma unroll
  for (int i = 0; i < 4; ++i)
    #pragma unroll
    for (int j = 0; j < 4; ++j) acc[i][j] = 0.f;
  #pragma unroll 4
  for (int k = 0; k < 64; ++k) {
    const float4 a = *reinterpret_cast<const float4*>(&Am[k * 64 + r0]);
    const float4 b = *reinterpret_cast<const float4*>(&Bm[k * 64 + c0]);
    const float av[4] = {a.x, a.y, a.z, a.w};
    const float bv[4] = {b.x, b.y, b.z, b.w};
    #pragma unroll
    for (int i = 0; i < 4; ++i)
      #pragma unroll
      for (int j = 0; j < 4; ++j) acc[i][j] += av[i] * bv[j];
  }
  float* Td = ws + offT(nblk) + (size_t)l * 4096;
  #pragma unroll
  for (int i = 0; i < 4; ++i) {
    float4 o;
    o.x = valid ? acc[i][0] : (((r0 + i) == (c0 + 0)) ? 1.f : 0.f);
    o.y = valid ? acc[i][1] : (((r0 + i) == (c0 + 1)) ? 1.f : 0.f);
    o.z = valid ? acc[i][2] : (((r0 + i) == (c0 + 2)) ? 1.f : 0.f);
    o.w = valid ? acc[i][3] : (((r0 + i) == (c0 + 3)) ? 1.f : 0.f);
    *reinterpret_cast<float4*>(&Td[(r0 + i) * 64 + c0]) = o;
    const float bp = o.x * mucS[c0] + o.y * mucS[c0 + 1] + o.z * mucS[c0 + 2] + o.w * mucS[c0 + 3];
    atomicAdd(&red[r0 + i], bp);
  }
  __syncthreads();
  if (tid < 64) ws[offBIAS(nblk) + l * 64 + tid] = valid ? (musS[tid] - red[tid]) : 0.f;
}

// =====================================================================
// SORT CHAIN: global counting sort of content pixels by label.
// =====================================================================
__global__ __launch_bounds__(256) void k_hist(const int* __restrict__ cseg,
                                              int* __restrict__ wsi, int nblk)
{
  __shared__ int h[8];
  const int tid = threadIdx.x;
  if (tid < 8) h[tid] = 0;
  __syncthreads();
  const int base = blockIdx.x * 1024;
  for (int s = 0; s < 4; ++s) atomicAdd(&h[cseg[base + s * 256 + tid]], 1);
  __syncthreads();
  if (tid < 8) wsi[offHISTi(nblk) + blockIdx.x * 8 + tid] = h[tid];
}

__global__ __launch_bounds__(256) void k_scan(int* __restrict__ wsi, int nblk)
{
  __shared__ int hv[2048], s1[128], p1[128], cntS[8], baseS[9];
  const int tid = threadIdx.x;
  for (int i = tid; i < 2048; i += 256) hv[i] = wsi[offHISTi(nblk) + i];
  __syncthreads();
  if (tid < 128) {            // level1: 16-block super-chunk sums
    const int sc = tid >> 3, l = tid & 7;
    int s = 0;
    for (int i = 0; i < 16; ++i) s += hv[(sc * 16 + i) * 8 + l];
    s1[tid] = s;
  }
  __syncthreads();
  if (tid < 128) {            // level2: exclusive prefix over super-chunks
    const int sc = tid >> 3, l = tid & 7;
    int p = 0;
    for (int j = 0; j < sc; ++j) p += s1[j * 8 + l];
    p1[tid] = p;
  }
  __syncthreads();
  if (tid < 8) cntS[tid] = p1[15 * 8 + tid] + s1[15 * 8 + tid];
  __syncthreads();
  if (tid == 0) {
    baseS[0] = 0;
    for (int l = 0; l < 8; ++l) baseS[l + 1] = baseS[l] + ((cntS[l] + 63) & ~63);
  }
  __syncthreads();
  {                           // level3: per-block per-label global offsets
    const int b = tid;
    for (int l = 0; l < 8; ++l) {
      int w = baseS[l] + p1[(b >> 4) * 8 + l];
      for (int b2 = (b & ~15); b2 < b; ++b2) w += hv[b2 * 8 + l];
      wsi[offOFFSi(nblk) + b * 8 + l] = w;
    }
  }
  const int ngrp = baseS[8] >> 6;
  if (tid == 0) wsi[offMETAi(nblk) + 0] = ngrp;
  if (tid < 9) wsi[offMETAi(nblk) + 1 + tid] = baseS[tid];
  if (tid < 8) wsi[offMETAi(nblk) + 10 + tid] = cntS[tid];
  for (int g = tid; g < ngrp; g += 256) {
    int lab = 0;
    for (int l = 1; l < 8; ++l) lab += (g * 64 >= baseS[l]) ? 1 : 0;
    wsi[offGRPLi(nblk) + g] = lab;
  }
}

__global__ __launch_bounds__(256) void k_scatter(const int* __restrict__ cseg,
                                                 int* __restrict__ wsi, int nblk)
{
  __shared__ int chcnt[16][8];
  const int tid = threadIdx.x, lane = tid & 63, wv = tid >> 6;
  const int base = blockIdx.x * 1024;
  int lb[4];
  for (int s = 0; s < 4; ++s) {
    lb[s] = cseg[base + s * 256 + tid];
    const int chunk = s * 4 + wv;
    for (int l = 0; l < 8; ++l) {
      unsigned long long m = __ballot(lb[s] == l);
      if (lane == 0) chcnt[chunk][l] = __popcll(m);
    }
  }
  __syncthreads();
  const unsigned long long mlt = (1ull << lane) - 1ull;
  for (int s = 0; s < 4; ++s) {
    const int chunk = s * 4 + wv;
    const int myl = lb[s];
    int rank = 0;
    for (int l = 0; l < 8; ++l) {
      unsigned long long m = __ballot(myl == l);
      if (l == myl) rank = __popcll(m & mlt);
    }
    int off = wsi[offOFFSi(nblk) + blockIdx.x * 8 + myl];
    for (int c = 0; c < chunk; ++c) off += chcnt[c][myl];
    wsi[offSIDXi(nblk) + off + rank] = base + s * 256 + tid;
  }
}

__global__ __launch_bounds__(64) void k_fill(int* __restrict__ wsi, int nblk)
{
  const int tid = threadIdx.x;
  for (int l = 0; l < 8; ++l) {
    const int cnt = wsi[offMETAi(nblk) + 10 + l];
    const int b0  = wsi[offMETAi(nblk) + 1 + l];
    const int b1  = wsi[offMETAi(nblk) + 2 + l];
    const int start = b0 + cnt;
    const int padn  = b1 - start;
    if (cnt > 0 && tid < padn)
      wsi[offSIDXi(nblk) + start + tid] = wsi[offSIDXi(nblk) + b0];
  }
}

// =====================================================================
// K3: apply y = T_lab x + bias_lab on label-sorted 64-pixel wave groups.
// Label is wave-uniform -> T rows come in via scalar (SMEM) loads and
// feed v_fma with SGPR operand: zero LDS, full VALU rate.
// =====================================================================
__global__ __launch_bounds__(512) void k_apply(
    const float* __restrict__ cont, const float* __restrict__ ws,
    const int* __restrict__ wsi, float* __restrict__ out, int nblk)
{
  const int tid = threadIdx.x, lane = tid & 63, wv = tid >> 6;
  const int g = blockIdx.x * 8 + wv;
  const int ngrp = wsi[offMETAi(nblk) + 0];
  if (g >= ngrp) return;

  const int lab = __builtin_amdgcn_readfirstlane(wsi[offGRPLi(nblk) + g]);
  const int p   = wsi[offSIDXi(nblk) + g * 64 + lane];

  float x[64];
  #pragma unroll
  for (int c = 0; c < 64; ++c) x[c] = cont[(size_t)c * NPIX + p];

  const float* __restrict__ Tb = ws + offT(nblk) + (size_t)lab * 4096;
  const float* __restrict__ Bb = ws + offBIAS(nblk) + (size_t)lab * 64;

  #pragma unroll 2
  for (int oc = 0; oc < 64; ++oc) {
    float a0 = Bb[oc], a1 = 0.f, a2 = 0.f, a3 = 0.f;
    const float* __restrict__ Tr = Tb + oc * 64;
    #pragma unroll
    for (int k4 = 0; k4 < 16; ++k4) {
      const float4 tv = *reinterpret_cast<const float4*>(&Tr[4 * k4]);
      a0 += tv.x * x[4 * k4 + 0];
      a1 += tv.y * x[4 * k4 + 1];
      a2 += tv.z * x[4 * k4 + 2];
      a3 += tv.w * x[4 * k4 + 3];
    }
    out[(size_t)oc * NPIX + p] = (a0 + a1) + (a2 + a3);
  }
}

// =====================================================================
extern "C" void kernel_launch(void* const* d_in, const int* in_sizes, int n_in,
                              void* d_out, int out_size, void* d_ws, size_t ws_size,
                              hipStream_t stream)
{
  const float* cont = (const float*)d_in[0];
  const float* styl = (const float*)d_in[1];
  const int*   cseg = (const int*)d_in[2];
  const int*   sseg = (const int*)d_in[3];
  float*       ws   = (float*)d_ws;
  int*         wsi  = (int*)d_ws;
  float*       out  = (float*)d_out;

  const size_t favail = ws_size / 4;
  int nblk = 128;
  while (nblk > 8 && offEnd(nblk) > favail) nblk >>= 1;

  // sort chain (only needs cseg)
  k_hist<<<dim3(256), 256, 0, stream>>>(cseg, wsi, nblk);
  k_scan<<<dim3(1), 256, 0, stream>>>(wsi, nblk);
  k_scatter<<<dim3(256), 256, 0, stream>>>(cseg, wsi, nblk);
  k_fill<<<dim3(1), 64, 0, stream>>>(wsi, nblk);
  // statistics chain
  k_moments<<<dim3(nblk, 2), 512, 0, stream>>>(cont, styl, cseg, sseg, ws, nblk);
  k_reduce<<<dim3(256), 256, 0, stream>>>(ws, nblk);
  k_ns<<<dim3(16), 256, 0, stream>>>(ws, nblk);
  k_tmat<<<dim3(8), 256, 0, stream>>>(ws, nblk);
  // apply on sorted groups (max groups = 4104 -> 513 blocks of 8 waves)
  k_apply<<<dim3(513), 512, 0, stream>>>(cont, ws, wsi, out, nblk);
}